// Round 2
// baseline (706.839 us; speedup 1.0000x reference)
//
#include <hip/hip_runtime.h>
#include <hip/hip_bf16.h>

typedef __attribute__((ext_vector_type(8))) short short8;
typedef __attribute__((ext_vector_type(4))) float floatx4;
typedef unsigned int u32;

__device__ __forceinline__ float bf2f(u32 u) {
    union { u32 u; float f; } c; c.u = u << 16; return c.f;
}
__device__ __forceinline__ u32 f2bf(float f) {
    union { float f; u32 u; } c; c.f = f;
    return (c.u + 0x7FFFu + ((c.u >> 16) & 1u)) >> 16;  // RNE
}
__device__ __forceinline__ short8 cvt8(const float* p) {
    float4 f0 = ((const float4*)p)[0];
    float4 f1 = ((const float4*)p)[1];
    short8 r;
    r[0] = (short)f2bf(f0.x); r[1] = (short)f2bf(f0.y);
    r[2] = (short)f2bf(f0.z); r[3] = (short)f2bf(f0.w);
    r[4] = (short)f2bf(f1.x); r[5] = (short)f2bf(f1.y);
    r[6] = (short)f2bf(f1.z); r[7] = (short)f2bf(f1.w);
    return r;
}

// ---------------- CSR build ----------------
__global__ void count_k(const int* __restrict__ dst, int* __restrict__ cnt, int E) {
    int i = blockIdx.x * 256 + threadIdx.x;
    if (i < E) atomicAdd(&cnt[dst[i]], 1);
}

__global__ void dinv_k(const int* __restrict__ cnt, float* __restrict__ dinv, int n) {
    int i = blockIdx.x * 256 + threadIdx.x;
    if (i < n) dinv[i] = rsqrtf((float)cnt[i] + 1.0f);  // +1 self-loop
}

__global__ void scan1_k(const int* __restrict__ cnt, int* __restrict__ incl,
                        int* __restrict__ bsum, int n) {
    __shared__ int tmp[256];
    int t = threadIdx.x;
    int idx = blockIdx.x * 256 + t;
    int v = (idx < n) ? cnt[idx] : 0;
    tmp[t] = v;
    __syncthreads();
    for (int off = 1; off < 256; off <<= 1) {
        int add = (t >= off) ? tmp[t - off] : 0;
        __syncthreads();
        tmp[t] += add;
        __syncthreads();
    }
    if (idx < n) incl[idx] = tmp[t];
    if (t == 255) bsum[blockIdx.x] = tmp[255];
}

__global__ void scan2_k(int* __restrict__ bsum, int nb) {
    __shared__ int tmp[1024];
    int t = threadIdx.x;
    int v = (t < nb) ? bsum[t] : 0;
    tmp[t] = v;
    __syncthreads();
    for (int off = 1; off < 1024; off <<= 1) {
        int add = (t >= off) ? tmp[t - off] : 0;
        __syncthreads();
        tmp[t] += add;
        __syncthreads();
    }
    if (t < nb) bsum[t] = tmp[t] - v;  // exclusive block offsets
}

__global__ void scan3_k(const int* __restrict__ cnt, const int* __restrict__ incl,
                        const int* __restrict__ bsum, int* __restrict__ rowptr,
                        int* __restrict__ cursor, int n, int E) {
    int idx = blockIdx.x * 256 + threadIdx.x;
    if (idx < n) {
        int ex = incl[idx] - cnt[idx] + bsum[blockIdx.x];
        rowptr[idx] = ex;
        cursor[idx] = ex;
    }
    if (blockIdx.x == 0 && threadIdx.x == 0) rowptr[n] = E;
}

__global__ void scatter_k(const int* __restrict__ src, const int* __restrict__ dst,
                          int* __restrict__ cursor, int* __restrict__ col, int E) {
    int i = blockIdx.x * 256 + threadIdx.x;
    if (i < E) {
        int p = atomicAdd(&cursor[dst[i]], 1);
        col[p] = src[i];
    }
}

// transpose + f32 -> bf16 convert (weights)
__global__ void transcvt_k(const float* __restrict__ in,
                           unsigned short* __restrict__ out, int rows, int cols) {
    int i = blockIdx.x * 256 + threadIdx.x;
    if (i < rows * cols) {
        int r = i / cols, c = i - r * cols;
        out[(size_t)c * rows + r] = (unsigned short)f2bf(in[i]);
    }
}

// ---------------- GEMM: out[M][NCOLS] = A[M][128] @ W[128][NCOLS], Wt pre-transposed bf16 ----------------
template <int NCOLS, bool BIAS, bool SIG, bool AF32, bool OUTF32>
__global__ __launch_bounds__(256) void gemm_k(const void* __restrict__ Av,
                                              const short* __restrict__ Wt,
                                              const float* __restrict__ bias,
                                              void* __restrict__ outv, int M) {
    int wave = threadIdx.x >> 6;
    int lane = threadIdx.x & 63;
    int m0 = blockIdx.x * 64 + wave * 16;
    if (m0 >= M) return;
    int quad = lane >> 4, lr = lane & 15;
    int row = m0 + lr;
    if (row >= M) row = M - 1;  // clamp loads; stores guarded
    short8 a0, a1, a2, a3;
    if (AF32) {
        const float* Ab = (const float*)Av + (size_t)row * 128 + quad * 8;
        a0 = cvt8(Ab); a1 = cvt8(Ab + 32); a2 = cvt8(Ab + 64); a3 = cvt8(Ab + 96);
    } else {
        const short8* Ap = (const short8*)((const short*)Av + (size_t)row * 128 + quad * 8);
        a0 = Ap[0]; a1 = Ap[4]; a2 = Ap[8]; a3 = Ap[12];
    }
#pragma unroll
    for (int nt = 0; nt < NCOLS / 16; ++nt) {
        int ncol = nt * 16 + lr;
        const short8* Bp = (const short8*)(Wt + (size_t)ncol * 128 + quad * 8);
        short8 b0 = Bp[0], b1 = Bp[4], b2 = Bp[8], b3 = Bp[12];
        floatx4 acc = {0.f, 0.f, 0.f, 0.f};
        acc = __builtin_amdgcn_mfma_f32_16x16x32_bf16(a0, b0, acc, 0, 0, 0);
        acc = __builtin_amdgcn_mfma_f32_16x16x32_bf16(a1, b1, acc, 0, 0, 0);
        acc = __builtin_amdgcn_mfma_f32_16x16x32_bf16(a2, b2, acc, 0, 0, 0);
        acc = __builtin_amdgcn_mfma_f32_16x16x32_bf16(a3, b3, acc, 0, 0, 0);
        float bv = BIAS ? bias[ncol] : 0.f;
#pragma unroll
        for (int r = 0; r < 4; ++r) {
            int orow = m0 + quad * 4 + r;  // D: col=lane&15, row=quad*4+r
            if (orow < M) {
                float v = acc[r] + bv;
                if (SIG) v = 1.f / (1.f + __expf(-v));
                if (OUTF32)
                    ((float*)outv)[(size_t)orow * NCOLS + ncol] = v;
                else
                    ((unsigned short*)outv)[(size_t)orow * NCOLS + ncol] =
                        (unsigned short)f2bf(v);
            }
        }
    }
}

// ---------------- fused aggregate + bias + relu (+ LayerNorm) ----------------
// one wave per node; lane handles feats {2*lane, 2*lane+1} (one dword of the bf16 row)
template <int MODE>  // 0: relu+LN, 1: relu only
__global__ __launch_bounds__(256) void agg_k(const u32* __restrict__ hw,
                                             const int* __restrict__ rowptr,
                                             const int* __restrict__ col,
                                             const float* __restrict__ dinv,
                                             const float* __restrict__ bias,
                                             const float* __restrict__ gam,
                                             const float* __restrict__ bet,
                                             u32* __restrict__ out, int n) {
    int lane = threadIdx.x & 63;
    int node = blockIdx.x * 4 + (threadIdx.x >> 6);
    if (node >= n) return;
    int beg = rowptr[node], end = rowptr[node + 1];
    float a0 = 0.f, a1 = 0.f;
    int e = beg;
    for (; e + 4 <= end; e += 4) {  // unroll-4 for memory-level parallelism
        int s0 = col[e], s1 = col[e + 1], s2 = col[e + 2], s3 = col[e + 3];
        float w0 = dinv[s0], w1 = dinv[s1], w2 = dinv[s2], w3 = dinv[s3];
        u32 v0 = hw[(size_t)s0 * 64 + lane];
        u32 v1 = hw[(size_t)s1 * 64 + lane];
        u32 v2 = hw[(size_t)s2 * 64 + lane];
        u32 v3 = hw[(size_t)s3 * 64 + lane];
        a0 += w0 * bf2f(v0 & 0xffff) + w1 * bf2f(v1 & 0xffff) +
              w2 * bf2f(v2 & 0xffff) + w3 * bf2f(v3 & 0xffff);
        a1 += w0 * bf2f(v0 >> 16) + w1 * bf2f(v1 >> 16) +
              w2 * bf2f(v2 >> 16) + w3 * bf2f(v3 >> 16);
    }
    for (; e < end; ++e) {
        int s = col[e];
        float w = dinv[s];
        u32 v = hw[(size_t)s * 64 + lane];
        a0 += w * bf2f(v & 0xffff);
        a1 += w * bf2f(v >> 16);
    }
    // out = dinv[i] * (sum + dinv[i]*hw[i]) + b   (self-loop folded in)
    float di = dinv[node];
    u32 vs = hw[(size_t)node * 64 + lane];
    a0 = di * (a0 + di * bf2f(vs & 0xffff));
    a1 = di * (a1 + di * bf2f(vs >> 16));
    a0 = fmaxf(a0 + bias[2 * lane], 0.f);
    a1 = fmaxf(a1 + bias[2 * lane + 1], 0.f);
    if (MODE == 0) {
        float s = a0 + a1, q = a0 * a0 + a1 * a1;
#pragma unroll
        for (int m = 32; m >= 1; m >>= 1) {
            s += __shfl_xor(s, m, 64);
            q += __shfl_xor(q, m, 64);
        }
        float mu = s * (1.f / 128.f);
        float var = q * (1.f / 128.f) - mu * mu;
        float rs = rsqrtf(fmaxf(var, 0.f) + 1e-5f);
        a0 = gam[2 * lane] * (a0 - mu) * rs + bet[2 * lane];
        a1 = gam[2 * lane + 1] * (a1 - mu) * rs + bet[2 * lane + 1];
    }
    out[(size_t)node * 64 + lane] = f2bf(a0) | (f2bf(a1) << 16);
}

extern "C" void kernel_launch(void* const* d_in, const int* in_sizes, int n_in,
                              void* d_out, int out_size, void* d_ws, size_t ws_size,
                              hipStream_t stream) {
    const int N = in_sizes[0] / 128;
    const int E = in_sizes[1] / 2;
    const int* edge = (const int*)d_in[1];
    const int* srcp = edge;          // edge_index[0]
    const int* dstp = edge + E;      // edge_index[1]
    const float* x   = (const float*)d_in[0];
    const float* W1  = (const float*)d_in[2];
    const float* b1  = (const float*)d_in[3];
    const float* W2  = (const float*)d_in[4];
    const float* b2  = (const float*)d_in[5];
    const float* W3  = (const float*)d_in[6];
    const float* b3  = (const float*)d_in[7];
    const float* g1  = (const float*)d_in[8];
    const float* be1 = (const float*)d_in[9];
    const float* g2  = (const float*)d_in[10];
    const float* be2 = (const float*)d_in[11];
    const float* Wp1 = (const float*)d_in[12];
    const float* bp1 = (const float*)d_in[13];
    const float* Wp2 = (const float*)d_in[14];
    const float* bp2 = (const float*)d_in[15];

    char* ws = (char*)d_ws;
    size_t off = 0;
    auto alloc = [&](size_t b) -> char* {
        char* p = ws + off;
        off += (b + 255) & ~(size_t)255;
        return p;
    };
    int* cnt    = (int*)alloc((size_t)N * 4);
    int* incl   = (int*)alloc((size_t)N * 4);
    int* rowptr = (int*)alloc((size_t)(N + 1) * 4);
    int* cursor = (int*)alloc((size_t)N * 4);
    int* bsum   = (int*)alloc(4096);
    float* dinv = (float*)alloc((size_t)N * 4);
    int* colA   = (int*)alloc((size_t)E * 4);
    unsigned short* hw  = (unsigned short*)alloc((size_t)N * 128 * 2);
    unsigned short* hb  = (unsigned short*)alloc((size_t)N * 128 * 2);
    unsigned short* w1t = (unsigned short*)alloc(128 * 128 * 2);
    unsigned short* w2t = (unsigned short*)alloc(128 * 128 * 2);
    unsigned short* w3t = (unsigned short*)alloc(128 * 128 * 2);
    unsigned short* wp1t = (unsigned short*)alloc(128 * 128 * 2);
    unsigned short* wp2t = (unsigned short*)alloc(64 * 128 * 2);
    if (off > ws_size) return;

    int nb = (N + 255) / 256;   // 391 <= 1024, scan2 single-block ok
    int eb = (E + 255) / 256;
    int gb = (N + 63) / 64;
    int ab = (N + 3) / 4;

    hipMemsetAsync(cnt, 0, (size_t)N * 4, stream);
    count_k<<<eb, 256, 0, stream>>>(dstp, cnt, E);
    dinv_k<<<nb, 256, 0, stream>>>(cnt, dinv, N);
    scan1_k<<<nb, 256, 0, stream>>>(cnt, incl, bsum, N);
    scan2_k<<<1, 1024, 0, stream>>>(bsum, nb);
    scan3_k<<<nb, 256, 0, stream>>>(cnt, incl, bsum, rowptr, cursor, N, E);
    scatter_k<<<eb, 256, 0, stream>>>(srcp, dstp, cursor, colA, E);
    transcvt_k<<<64, 256, 0, stream>>>(W1, w1t, 128, 128);
    transcvt_k<<<64, 256, 0, stream>>>(W2, w2t, 128, 128);
    transcvt_k<<<64, 256, 0, stream>>>(W3, w3t, 128, 128);
    transcvt_k<<<64, 256, 0, stream>>>(Wp1, wp1t, 128, 128);
    transcvt_k<<<32, 256, 0, stream>>>(Wp2, wp2t, 128, 64);

    // conv1: hw = x@W1 ; h = LN(relu(agg(hw)+b1))
    gemm_k<128, false, false, true, false><<<gb, 256, 0, stream>>>(
        x, (const short*)w1t, nullptr, hw, N);
    agg_k<0><<<ab, 256, 0, stream>>>((const u32*)hw, rowptr, colA, dinv, b1, g1, be1,
                                     (u32*)hb, N);
    // conv2
    gemm_k<128, false, false, false, false><<<gb, 256, 0, stream>>>(
        hb, (const short*)w2t, nullptr, hw, N);
    agg_k<0><<<ab, 256, 0, stream>>>((const u32*)hw, rowptr, colA, dinv, b2, g2, be2,
                                     (u32*)hb, N);
    // conv3 (relu only)
    gemm_k<128, false, false, false, false><<<gb, 256, 0, stream>>>(
        hb, (const short*)w3t, nullptr, hw, N);
    agg_k<1><<<ab, 256, 0, stream>>>((const u32*)hw, rowptr, colA, dinv, b3, g1, be1,
                                     (u32*)hb, N);
    // MLP head: (h@Wp1+bp1)@Wp2+bp2 -> sigmoid
    gemm_k<128, true, false, false, false><<<gb, 256, 0, stream>>>(
        hb, (const short*)wp1t, bp1, hw, N);
    gemm_k<64, true, true, false, true><<<gb, 256, 0, stream>>>(
        hw, (const short*)wp2t, bp2, d_out, N);
}

// Round 3
// 552.988 us; speedup vs baseline: 1.2782x; 1.2782x over previous
//
#include <hip/hip_runtime.h>
#include <hip/hip_bf16.h>

typedef __attribute__((ext_vector_type(8))) short short8;
typedef __attribute__((ext_vector_type(4))) float floatx4;
typedef unsigned int u32;

#define EPB 8192  // edges per block in bucket_k

__device__ __forceinline__ float bf2f(u32 u) {
    union { u32 u; float f; } c; c.u = u << 16; return c.f;
}
__device__ __forceinline__ u32 f2bf(float f) {
    union { float f; u32 u; } c; c.f = f;
    return (c.u + 0x7FFFu + ((c.u >> 16) & 1u)) >> 16;  // RNE
}
__device__ __forceinline__ short8 cvt8(const float* p) {
    float4 f0 = ((const float4*)p)[0];
    float4 f1 = ((const float4*)p)[1];
    short8 r;
    r[0] = (short)f2bf(f0.x); r[1] = (short)f2bf(f0.y);
    r[2] = (short)f2bf(f0.z); r[3] = (short)f2bf(f0.w);
    r[4] = (short)f2bf(f1.x); r[5] = (short)f2bf(f1.y);
    r[6] = (short)f2bf(f1.z); r[7] = (short)f2bf(f1.w);
    return r;
}

// ---------------- CSR build: LDS-staged bucket sort (256 dst nodes / bucket) ----------------
// k1: global bucket histogram (LDS-aggregated)
__global__ __launch_bounds__(256) void hist_k(const int* __restrict__ dst,
                                              int* __restrict__ bcnt, int E) {
    __shared__ int h[512];
    int t = threadIdx.x;
    h[t] = 0; h[t + 256] = 0;
    __syncthreads();
    int e0 = blockIdx.x * 4096;
    int ne = min(4096, E - e0);
    for (int i = t; i < ne; i += 256) atomicAdd(&h[dst[e0 + i] >> 8], 1);
    __syncthreads();
    int c = h[t];
    if (c) atomicAdd(&bcnt[t], c);
    c = h[t + 256];
    if (c) atomicAdd(&bcnt[t + 256], c);
}

// k2: exclusive scan of bucket counts (single block, 512 threads)
__global__ void bscan_k(const int* __restrict__ bcnt, int* __restrict__ bbase,
                        int* __restrict__ cursor, int nb, int E) {
    __shared__ int tmp[512];
    int t = threadIdx.x;
    int v = (t < nb) ? bcnt[t] : 0;
    tmp[t] = v;
    __syncthreads();
    for (int off = 1; off < 512; off <<= 1) {
        int a = (t >= off) ? tmp[t - off] : 0;
        __syncthreads();
        tmp[t] += a;
        __syncthreads();
    }
    if (t < nb) {
        int ex = tmp[t] - v;
        bbase[t] = ex;
        cursor[t] = ex;
    }
    if (t == 0) bbase[nb] = E;
}

// k3: stage edges by bucket in LDS, write coalesced bursts to reserved ranges
__global__ __launch_bounds__(256) void bucket_k(const int* __restrict__ src,
                                                const int* __restrict__ dst,
                                                int* __restrict__ cursor,
                                                u32* __restrict__ pairs, int E, int nb) {
    __shared__ int cnt[512];
    __shared__ int incl[512];
    __shared__ int cur[512];
    __shared__ int gb[512];
    __shared__ u32 stage[EPB];
    int t = threadIdx.x;
    int s0 = t, s1 = t + 256;
    cnt[s0] = 0; cnt[s1] = 0;
    __syncthreads();
    int e0 = blockIdx.x * EPB;
    int ne = min(EPB, E - e0);
    for (int i = t; i < ne; i += 256) atomicAdd(&cnt[dst[e0 + i] >> 8], 1);
    __syncthreads();
    incl[s0] = cnt[s0]; incl[s1] = cnt[s1];
    __syncthreads();
    for (int off = 1; off < 512; off <<= 1) {
        int a0 = (s0 >= off) ? incl[s0 - off] : 0;
        int a1 = (s1 >= off) ? incl[s1 - off] : 0;
        __syncthreads();
        incl[s0] += a0; incl[s1] += a1;
        __syncthreads();
    }
    for (int b = t; b < nb; b += 256) {
        int c = cnt[b];
        cur[b] = incl[b] - c;  // local exclusive
        gb[b] = c ? atomicAdd(&cursor[b], c) : 0;
    }
    __syncthreads();
    for (int i = t; i < ne; i += 256) {
        int d = dst[e0 + i];
        int s = src[e0 + i];
        int b = d >> 8;
        int p = atomicAdd(&cur[b], 1);
        stage[p] = (u32)s | ((u32)(d & 255) << 24);
    }
    __syncthreads();
    for (int j = t; j < ne; j += 256) {
        int lo = 0, hi = nb;  // first bucket with incl > j
        while (lo < hi) {
            int mid = (lo + hi) >> 1;
            if (incl[mid] <= j) lo = mid + 1; else hi = mid;
        }
        int b = lo;
        int ex = incl[b] - cnt[b];
        pairs[gb[b] + (j - ex)] = stage[j];
    }
}

// k4: per-bucket rowptr/dinv/col build (all writes within a 16KB L2-local window)
__global__ __launch_bounds__(256) void build_k(const u32* __restrict__ pairs,
                                               const int* __restrict__ bbase,
                                               int* __restrict__ rowptr,
                                               float* __restrict__ dinv,
                                               int* __restrict__ col, int N, int E) {
    __shared__ int cnt[256], incl[256], cur[256];
    int b = blockIdx.x, t = threadIdx.x;
    int base = bbase[b];
    int ecnt = bbase[b + 1] - base;
    cnt[t] = 0;
    __syncthreads();
    for (int j = t; j < ecnt; j += 256) atomicAdd(&cnt[pairs[base + j] >> 24], 1);
    __syncthreads();
    incl[t] = cnt[t];
    __syncthreads();
    for (int off = 1; off < 256; off <<= 1) {
        int a = (t >= off) ? incl[t - off] : 0;
        __syncthreads();
        incl[t] += a;
        __syncthreads();
    }
    int ex = incl[t] - cnt[t];
    int node = b * 256 + t;
    if (node < N) {
        rowptr[node] = base + ex;
        dinv[node] = rsqrtf((float)cnt[t] + 1.0f);  // +1 self-loop
    }
    cur[t] = ex;
    if (b == 0 && t == 0) rowptr[N] = E;
    __syncthreads();
    for (int j = t; j < ecnt; j += 256) {
        u32 v = pairs[base + j];
        int dl = v >> 24;
        int r = atomicAdd(&cur[dl], 1);
        col[base + r] = (int)(v & 0xFFFFFF);
    }
}

// transpose + f32 -> bf16 convert (weights)
__global__ void transcvt_k(const float* __restrict__ in,
                           unsigned short* __restrict__ out, int rows, int cols) {
    int i = blockIdx.x * 256 + threadIdx.x;
    if (i < rows * cols) {
        int r = i / cols, c = i - r * cols;
        out[(size_t)c * rows + r] = (unsigned short)f2bf(in[i]);
    }
}

// ---------------- GEMM: out[M][NCOLS] = A[M][128] @ W[128][NCOLS] (Wt bf16, pre-T) ----------------
// DINV: scale output row r by dinv[r] (folds GCN src normalization into hw')
template <int NCOLS, bool BIAS, bool SIG, bool AF32, bool OUTF32, bool DINV>
__global__ __launch_bounds__(256) void gemm_k(const void* __restrict__ Av,
                                              const short* __restrict__ Wt,
                                              const float* __restrict__ bias,
                                              const float* __restrict__ dinv,
                                              void* __restrict__ outv, int M) {
    int wave = threadIdx.x >> 6;
    int lane = threadIdx.x & 63;
    int m0 = blockIdx.x * 64 + wave * 16;
    if (m0 >= M) return;
    int quad = lane >> 4, lr = lane & 15;
    int row = m0 + lr;
    if (row >= M) row = M - 1;  // clamp loads; stores guarded
    short8 a0, a1, a2, a3;
    if (AF32) {
        const float* Ab = (const float*)Av + (size_t)row * 128 + quad * 8;
        a0 = cvt8(Ab); a1 = cvt8(Ab + 32); a2 = cvt8(Ab + 64); a3 = cvt8(Ab + 96);
    } else {
        const short8* Ap = (const short8*)((const short*)Av + (size_t)row * 128 + quad * 8);
        a0 = Ap[0]; a1 = Ap[4]; a2 = Ap[8]; a3 = Ap[12];
    }
#pragma unroll
    for (int nt = 0; nt < NCOLS / 16; ++nt) {
        int ncol = nt * 16 + lr;
        const short8* Bp = (const short8*)(Wt + (size_t)ncol * 128 + quad * 8);
        short8 b0 = Bp[0], b1 = Bp[4], b2 = Bp[8], b3 = Bp[12];
        floatx4 acc = {0.f, 0.f, 0.f, 0.f};
        acc = __builtin_amdgcn_mfma_f32_16x16x32_bf16(a0, b0, acc, 0, 0, 0);
        acc = __builtin_amdgcn_mfma_f32_16x16x32_bf16(a1, b1, acc, 0, 0, 0);
        acc = __builtin_amdgcn_mfma_f32_16x16x32_bf16(a2, b2, acc, 0, 0, 0);
        acc = __builtin_amdgcn_mfma_f32_16x16x32_bf16(a3, b3, acc, 0, 0, 0);
        float bv = BIAS ? bias[ncol] : 0.f;
#pragma unroll
        for (int r = 0; r < 4; ++r) {
            int orow = m0 + quad * 4 + r;  // D: col=lane&15, row=quad*4+r
            if (orow < M) {
                float v = acc[r];
                if (DINV) v *= dinv[orow];
                v += bv;
                if (SIG) v = 1.f / (1.f + __expf(-v));
                if (OUTF32)
                    ((float*)outv)[(size_t)orow * NCOLS + ncol] = v;
                else
                    ((unsigned short*)outv)[(size_t)orow * NCOLS + ncol] =
                        (unsigned short)f2bf(v);
            }
        }
    }
}

// ---------------- fused aggregate + bias + relu (+ LayerNorm) ----------------
// hw rows are pre-scaled by dinv[src]; out = dinv[i]*(sum_neighbors + self) + b
// one wave per node; lane handles feats {2*lane, 2*lane+1}; col broadcast via shfl
template <int MODE>  // 0: relu+LN, 1: relu only
__global__ __launch_bounds__(256) void agg_k(const u32* __restrict__ hw,
                                             const int* __restrict__ rowptr,
                                             const int* __restrict__ col,
                                             const float* __restrict__ dinv,
                                             const float* __restrict__ bias,
                                             const float* __restrict__ gam,
                                             const float* __restrict__ bet,
                                             u32* __restrict__ out, int n) {
    int lane = threadIdx.x & 63;
    int node = blockIdx.x * 4 + (threadIdx.x >> 6);
    if (node >= n) return;
    int beg = rowptr[node], end = rowptr[node + 1];
    float a0 = 0.f, a1 = 0.f;
    for (int c = beg; c < end; c += 64) {
        int idx = c + lane;
        int sv = (idx < end) ? col[idx] : 0;
        int m = end - c;
        if (m > 64) m = 64;
        int e = 0;
        for (; e + 8 <= m; e += 8) {  // 8 gathers in flight
            int t0 = __shfl(sv, e),     t1 = __shfl(sv, e + 1);
            int t2 = __shfl(sv, e + 2), t3 = __shfl(sv, e + 3);
            int t4 = __shfl(sv, e + 4), t5 = __shfl(sv, e + 5);
            int t6 = __shfl(sv, e + 6), t7 = __shfl(sv, e + 7);
            u32 v0 = hw[(size_t)t0 * 64 + lane];
            u32 v1 = hw[(size_t)t1 * 64 + lane];
            u32 v2 = hw[(size_t)t2 * 64 + lane];
            u32 v3 = hw[(size_t)t3 * 64 + lane];
            u32 v4 = hw[(size_t)t4 * 64 + lane];
            u32 v5 = hw[(size_t)t5 * 64 + lane];
            u32 v6 = hw[(size_t)t6 * 64 + lane];
            u32 v7 = hw[(size_t)t7 * 64 + lane];
            a0 += bf2f(v0 & 0xffff) + bf2f(v1 & 0xffff) + bf2f(v2 & 0xffff) +
                  bf2f(v3 & 0xffff) + bf2f(v4 & 0xffff) + bf2f(v5 & 0xffff) +
                  bf2f(v6 & 0xffff) + bf2f(v7 & 0xffff);
            a1 += bf2f(v0 >> 16) + bf2f(v1 >> 16) + bf2f(v2 >> 16) +
                  bf2f(v3 >> 16) + bf2f(v4 >> 16) + bf2f(v5 >> 16) +
                  bf2f(v6 >> 16) + bf2f(v7 >> 16);
        }
        for (; e < m; ++e) {
            int s = __shfl(sv, e);
            u32 v = hw[(size_t)s * 64 + lane];
            a0 += bf2f(v & 0xffff);
            a1 += bf2f(v >> 16);
        }
    }
    float di = dinv[node];
    u32 vs = hw[(size_t)node * 64 + lane];
    a0 = di * (a0 + bf2f(vs & 0xffff));
    a1 = di * (a1 + bf2f(vs >> 16));
    a0 = fmaxf(a0 + bias[2 * lane], 0.f);
    a1 = fmaxf(a1 + bias[2 * lane + 1], 0.f);
    if (MODE == 0) {
        float s = a0 + a1, q = a0 * a0 + a1 * a1;
#pragma unroll
        for (int m = 32; m >= 1; m >>= 1) {
            s += __shfl_xor(s, m, 64);
            q += __shfl_xor(q, m, 64);
        }
        float mu = s * (1.f / 128.f);
        float var = q * (1.f / 128.f) - mu * mu;
        float rs = rsqrtf(fmaxf(var, 0.f) + 1e-5f);
        a0 = gam[2 * lane] * (a0 - mu) * rs + bet[2 * lane];
        a1 = gam[2 * lane + 1] * (a1 - mu) * rs + bet[2 * lane + 1];
    }
    out[(size_t)node * 64 + lane] = f2bf(a0) | (f2bf(a1) << 16);
}

extern "C" void kernel_launch(void* const* d_in, const int* in_sizes, int n_in,
                              void* d_out, int out_size, void* d_ws, size_t ws_size,
                              hipStream_t stream) {
    const int N = in_sizes[0] / 128;
    const int E = in_sizes[1] / 2;
    const int nb = (N + 255) >> 8;  // buckets of 256 dst nodes
    const int* edge = (const int*)d_in[1];
    const int* srcp = edge;          // edge_index[0]
    const int* dstp = edge + E;      // edge_index[1]
    const float* x   = (const float*)d_in[0];
    const float* W1  = (const float*)d_in[2];
    const float* b1  = (const float*)d_in[3];
    const float* W2  = (const float*)d_in[4];
    const float* b2  = (const float*)d_in[5];
    const float* W3  = (const float*)d_in[6];
    const float* b3  = (const float*)d_in[7];
    const float* g1  = (const float*)d_in[8];
    const float* be1 = (const float*)d_in[9];
    const float* g2  = (const float*)d_in[10];
    const float* be2 = (const float*)d_in[11];
    const float* Wp1 = (const float*)d_in[12];
    const float* bp1 = (const float*)d_in[13];
    const float* Wp2 = (const float*)d_in[14];
    const float* bp2 = (const float*)d_in[15];

    char* ws = (char*)d_ws;
    size_t off = 0;
    auto alloc = [&](size_t b) -> char* {
        char* p = ws + off;
        off += (b + 255) & ~(size_t)255;
        return p;
    };
    int* bcnt   = (int*)alloc(512 * 4);
    int* bbase  = (int*)alloc((size_t)(nb + 1) * 4);
    int* cursor = (int*)alloc((size_t)nb * 4);
    int* rowptr = (int*)alloc((size_t)(N + 1) * 4);
    float* dinv = (float*)alloc((size_t)N * 4);
    u32* pairs  = (u32*)alloc((size_t)E * 4);
    int* colA   = (int*)alloc((size_t)E * 4);
    unsigned short* hw  = (unsigned short*)alloc((size_t)N * 128 * 2);
    unsigned short* hb  = (unsigned short*)alloc((size_t)N * 128 * 2);
    unsigned short* w1t = (unsigned short*)alloc(128 * 128 * 2);
    unsigned short* w2t = (unsigned short*)alloc(128 * 128 * 2);
    unsigned short* w3t = (unsigned short*)alloc(128 * 128 * 2);
    unsigned short* wp1t = (unsigned short*)alloc(128 * 128 * 2);
    unsigned short* wp2t = (unsigned short*)alloc(64 * 128 * 2);
    if (off > ws_size) return;

    int gb = (N + 63) / 64;
    int ab = (N + 3) / 4;

    hipMemsetAsync(bcnt, 0, 512 * 4, stream);
    hist_k<<<(E + 4095) / 4096, 256, 0, stream>>>(dstp, bcnt, E);
    bscan_k<<<1, 512, 0, stream>>>(bcnt, bbase, cursor, nb, E);
    bucket_k<<<(E + EPB - 1) / EPB, 256, 0, stream>>>(srcp, dstp, cursor, pairs, E, nb);
    build_k<<<nb, 256, 0, stream>>>(pairs, bbase, rowptr, dinv, colA, N, E);
    transcvt_k<<<64, 256, 0, stream>>>(W1, w1t, 128, 128);
    transcvt_k<<<64, 256, 0, stream>>>(W2, w2t, 128, 128);
    transcvt_k<<<64, 256, 0, stream>>>(W3, w3t, 128, 128);
    transcvt_k<<<64, 256, 0, stream>>>(Wp1, wp1t, 128, 128);
    transcvt_k<<<32, 256, 0, stream>>>(Wp2, wp2t, 128, 64);

    // conv1: hw = (x@W1)*dinv ; h = LN(relu(dinv*(agg+self)+b1))
    gemm_k<128, false, false, true, false, true><<<gb, 256, 0, stream>>>(
        x, (const short*)w1t, nullptr, dinv, hw, N);
    agg_k<0><<<ab, 256, 0, stream>>>((const u32*)hw, rowptr, colA, dinv, b1, g1, be1,
                                     (u32*)hb, N);
    // conv2
    gemm_k<128, false, false, false, false, true><<<gb, 256, 0, stream>>>(
        hb, (const short*)w2t, nullptr, dinv, hw, N);
    agg_k<0><<<ab, 256, 0, stream>>>((const u32*)hw, rowptr, colA, dinv, b2, g2, be2,
                                     (u32*)hb, N);
    // conv3 (relu only)
    gemm_k<128, false, false, false, false, true><<<gb, 256, 0, stream>>>(
        hb, (const short*)w3t, nullptr, dinv, hw, N);
    agg_k<1><<<ab, 256, 0, stream>>>((const u32*)hw, rowptr, colA, dinv, b3, g1, be1,
                                     (u32*)hb, N);
    // MLP head: (h@Wp1+bp1)@Wp2+bp2 -> sigmoid
    gemm_k<128, true, false, false, false, false><<<gb, 256, 0, stream>>>(
        hb, (const short*)wp1t, bp1, nullptr, hw, N);
    gemm_k<64, true, true, false, true, false><<<gb, 256, 0, stream>>>(
        hw, (const short*)wp2t, bp2, nullptr, d_out, N);
}